// Round 17
// baseline (122.898 us; speedup 1.0000x reference)
//
#include <hip/hip_runtime.h>
#include <math.h>

#define G  17
#define Cg 32
#define B  4
#define C  544
#define H  96
#define W  96
#define HW (H*W)
#define TILES 36         // 6x6 tiles of 16x16 px
#define NBLK (B*G*TILES) // 2448 (divisible by 8)
#define BN_EPS 1e-5f

typedef float    f32x4  __attribute__((ext_vector_type(4)));
typedef short    short8 __attribute__((ext_vector_type(8)));
typedef _Float16 h2     __attribute__((ext_vector_type(2)));
typedef _Float16 h8     __attribute__((ext_vector_type(8)));

// ---- fused-kernel LDS layout: zero-padded WIN=22 window + w_def B +
// w_off B (6 rows). AffS (3072B) ALIASES the w_off region after a barrier.
#define WIN       22
#define HALO      3
#define WPOS      (WIN*WIN)       // 484
#define W_STRIDE  80              // 16B-aligned; (pos*20)%32 -> 8 bank starts
#define W_BYTES   (WPOS*W_STRIDE) // 38720
#define B_STRIDE  592
#define B_BYTES   (Cg*B_STRIDE)   // 18944
#define WO_BYTES  (6*B_STRIDE)    // 3552 (>= AFFS 3072, aliased)
#define SMEM_BYTES (W_BYTES + B_BYTES + WO_BYTES) // 61216 <= 64K static

// XCD-chunked swizzle (round-4 verified: FETCH 925->87 MB).
__device__ __forceinline__ int swizzle_blk(int blk) {
    return (blk & 7) * (NBLK / 8) + (blk >> 3);
}

// ---------------------------------------------------------------------------
// FULLY FUSED kernel (no transpose pass, no workspace):
//  1) stage 22x22x32 fp16 window straight from NCHW f32 x: float4 row
//     segments (aligned: w0-4 ≡ 0 mod 4), cvt->fp16, 4x ds_write_b16
//     scatter; zero-padded (= conv zero-pad AND weight-0 sampling corners).
//  2) offset conv via MFMA (A = window rows at integer taps).
//  3) aff redistribute via AffS (aliases w_off LDS after barrier).
//  4) R15 streamlined deformable sampling + MFMA + BN + residual ReLU.
// ---------------------------------------------------------------------------
__global__ __launch_bounds__(256) void fused_deform_kernel(
    const float* __restrict__ x, const float* __restrict__ w_off,
    const float* __restrict__ b_off, const float* __restrict__ w_def,
    const float* __restrict__ gamma, const float* __restrict__ beta,
    const float* __restrict__ rmean, const float* __restrict__ rvar,
    float* __restrict__ out)
{
    __shared__ __align__(16) char smem[SMEM_BYTES];
    char* Wsm  = smem;                      // window (zero-padded)
    char* Bsm  = smem + W_BYTES;            // w_def fp16 [o][K]
    char* Wo   = smem + W_BYTES + B_BYTES;  // w_off fp16 [o<6][K]; later AffS
    char* AffS = Wo;

    const int blk  = swizzle_blk(blockIdx.x);
    const int tile = blk % TILES;
    const int g    = (blk / TILES) % G;
    const int b    = blk / (TILES*G);
    const int ty   = tile / 6, tx = tile % 6;
    const int h0   = ty*16,    w0 = tx*16;
    const int tid  = threadIdx.x;
    const int lane = tid & 63;
    const int wv   = tid >> 6;
    const int r15  = lane & 15;
    const int koff = lane >> 4;
    const int kb   = koff*16;   // byte offset of this lane's 8-ch slice

    const float* xg = x + ((size_t)b*C + g*Cg)*HW;

    // ---- 1) stage window from x: 32ch x 22rows x 6 float4 segs ----
    for (int i = tid; i < 32*22*6; i += 256) {
        const int ch  = i / 132;
        const int rem = i - ch*132;
        const int wy  = rem / 6;
        const int seg = rem - wy*6;
        const int y   = h0 + wy - HALO;            // image row
        const int cb  = w0 - 4 + seg*4;            // image col of float4 base (4-aligned)
        f32x4 v = (f32x4){0.f, 0.f, 0.f, 0.f};
        if ((unsigned)y < H) {
            if (cb >= 0 && cb + 3 < W) {
                v = *(const f32x4*)(xg + (size_t)ch*HW + y*W + cb);
            } else {
                const float* row = xg + (size_t)ch*HW + y*W;
                #pragma unroll
                for (int j = 0; j < 4; ++j) {
                    const int c = cb + j;
                    if ((unsigned)c < W) v[j] = row[c];
                }
            }
        }
        #pragma unroll
        for (int j = 0; j < 4; ++j) {
            const int wx = seg*4 + j - 1;
            if ((unsigned)wx < WIN)
                *(_Float16*)(Wsm + (wy*WIN + wx)*W_STRIDE + ch*2) = (_Float16)v[j];
        }
    }
    // ---- stage w_def to LDS (fp16): Bsm[o][K=t*32+i] ----
    for (int l = tid; l < Cg*288; l += 256) {
        const int o = l / 288, K = l % 288;
        const int t = K >> 5, i = K & 31;
        const float wt = w_def[(size_t)(g*Cg + o)*(Cg*9) + i*9 + t];
        *(_Float16*)(Bsm + o*B_STRIDE + K*2) = (_Float16)wt;
    }
    // ---- stage w_off to LDS (fp16): Wo[o<6][K=t*32+i] ----
    for (int l = tid; l < 6*288; l += 256) {
        const int o = l / 288, K = l % 288;
        const int t = K >> 5, i = K & 31;
        const float wt = w_off[(size_t)(g*6 + o)*288 + i*9 + t];
        *(_Float16*)(Wo + o*B_STRIDE + K*2) = (_Float16)wt;
    }
    __syncthreads();

    // ---- 2) offset conv via MFMA (R12/R14-verified maps) ----
    f32x4 acc_off[4];
    #pragma unroll
    for (int m = 0; m < 4; ++m) acc_off[m] = (f32x4){0.f, 0.f, 0.f, 0.f};

    #pragma unroll
    for (int t = 0; t < 9; ++t) {
        const int dy = t/3 - 1, dx = t%3 - 1;
        h8 bo = (h8){0,0,0,0,0,0,0,0};
        if (r15 < 6) bo = *(const h8*)(Wo + r15*B_STRIDE + t*64 + kb);
        #pragma unroll
        for (int m = 0; m < 4; ++m) {
            const int wr = wv*4 + m + dy + HALO;
            const int wc = r15 + dx + HALO;
            const h8 a = *(const h8*)(Wsm + (wr*WIN + wc)*W_STRIDE + kb);
            acc_off[m] = __builtin_amdgcn_mfma_f32_16x16x32_f16(a, bo, acc_off[m], 0, 0, 0);
        }
    }
    __syncthreads();   // all offset MFMAs done -> safe to overwrite Wo

    // ---- 3) redistribute aff: D[col=r15 -> ch][row=koff*4+r -> px col] ----
    if (r15 < 6) {
        #pragma unroll
        for (int m = 0; m < 4; ++m)
            #pragma unroll
            for (int r = 0; r < 4; ++r) {
                const int lp = (wv*4 + m)*16 + koff*4 + r;
                *(_Float16*)(AffS + lp*12 + r15*2) = (_Float16)acc_off[m][r];
            }
    }
    __syncthreads();

    // ---- readback + bias, pre-folded into window space ----
    const float bo0 = b_off[g*6+0], bo1 = b_off[g*6+1], bo2 = b_off[g*6+2];
    const float bo3 = b_off[g*6+3], bo4 = b_off[g*6+4], bo5 = b_off[g*6+5];
    float a0p[4], a1v[4], a2w[4], a3v[4], a4p[4], a5w[4];
    #pragma unroll
    for (int m = 0; m < 4; ++m) {
        const int row = wv*4 + m;
        const int lp = row*16 + r15;
        const h2 p01 = *(const h2*)(AffS + lp*12);
        const h2 p23 = *(const h2*)(AffS + lp*12 + 4);
        const h2 p45 = *(const h2*)(AffS + lp*12 + 8);
        a0p[m] = (float)p01[0] + bo0 + 1.0f;
        a1v[m] = (float)p01[1] + bo1;
        a2w[m] = (float)p23[0] + bo2 + (float)(row + HALO);
        a3v[m] = (float)p23[1] + bo3;
        a4p[m] = (float)p45[0] + bo4 + 1.0f;
        a5w[m] = (float)p45[1] + bo5 + (float)(r15 + HALO);
    }

    // ---- 4) deformable sampling + MFMA (R15 streamlined loop) ----
    f32x4 acc[4][2];
    #pragma unroll
    for (int m = 0; m < 4; ++m)
        #pragma unroll
        for (int n = 0; n < 2; ++n)
            acc[m][n] = (f32x4){0.f, 0.f, 0.f, 0.f};

    #pragma unroll 1
    for (int t = 0; t < 9; ++t) {
        const float kyf = (float)(t/3 - 1);
        const float kxf = (float)(t%3 - 1);

        h8 af[4];
        #pragma unroll
        for (int m = 0; m < 4; ++m) {
            const float pyw = fmaf(a0p[m], kyf, fmaf(a1v[m], kxf, a2w[m]));
            const float pxw = fmaf(a3v[m], kyf, fmaf(a4p[m], kxf, a5w[m]));
            const float y0f = floorf(pyw), x0f = floorf(pxw);
            const float fy = pyw - y0f,   fx = pxw - x0f;
            int iy = (int)y0f, ix = (int)x0f;
            iy = min(max(iy, 0), WIN-2);          // never binds (safety, med3)
            ix = min(max(ix, 0), WIN-2);
            const float gy = 1.0f - fy, gx = 1.0f - fx;
            const float w00 = gy*gx, w01 = gy*fx, w10 = fy*gx, w11 = fy*fx;
            const _Float16 h00 = (_Float16)w00, h01 = (_Float16)w01;
            const _Float16 h10 = (_Float16)w10, h11 = (_Float16)w11;
            const h2 W00 = (h2){h00, h00}, W01 = (h2){h01, h01};
            const h2 W10 = (h2){h10, h10}, W11 = (h2){h11, h11};

            const char* base = Wsm + (iy*WIN + ix)*W_STRIDE + kb;
            union { short8 s; h2 h[4]; h8 v; } u00, u01, u10, u11, r;
            u00.s = *(const short8*)(base);
            u01.s = *(const short8*)(base + W_STRIDE);
            u10.s = *(const short8*)(base + WIN*W_STRIDE);
            u11.s = *(const short8*)(base + WIN*W_STRIDE + W_STRIDE);

            #pragma unroll
            for (int j = 0; j < 4; ++j)
                r.h[j] = W00*u00.h[j] + W01*u01.h[j] + W10*u10.h[j] + W11*u11.h[j];
            af[m] = r.v;
        }

        #pragma unroll
        for (int n = 0; n < 2; ++n) {
            const h8 bf = *(const h8*)(Bsm + (n*16 + r15)*B_STRIDE + t*64 + kb);
            #pragma unroll
            for (int m = 0; m < 4; ++m)
                acc[m][n] = __builtin_amdgcn_mfma_f32_16x16x32_f16(af[m], bf, acc[m][n], 0, 0, 0);
        }
    }

    // ---- epilogue: BN params hoisted (2 rsqrt), residual + ReLU ----
    float scl[2], shf[2];
    #pragma unroll
    for (int n = 0; n < 2; ++n) {
        const int c = g*Cg + n*16 + r15;
        const float inv = rsqrtf(rvar[c] + BN_EPS);
        scl[n] = inv * gamma[c];
        shf[n] = beta[c] - rmean[c]*scl[n];
    }
    #pragma unroll
    for (int m = 0; m < 4; ++m) {
        const int row = wv*4 + m;
        const int pxg = (h0 + row)*W + w0 + koff*4;     // D row=(lane>>4)*4+reg
        #pragma unroll
        for (int n = 0; n < 2; ++n) {
            const int c = g*Cg + n*16 + r15;
            const size_t base = ((size_t)b*C + c)*HW + pxg;
            const float4 res = *(const float4*)(x + base);
            float4 ov;
            ov.x = fmaxf(fmaf(acc[m][n][0], scl[n], shf[n]) + res.x, 0.0f);
            ov.y = fmaxf(fmaf(acc[m][n][1], scl[n], shf[n]) + res.y, 0.0f);
            ov.z = fmaxf(fmaf(acc[m][n][2], scl[n], shf[n]) + res.z, 0.0f);
            ov.w = fmaxf(fmaf(acc[m][n][3], scl[n], shf[n]) + res.w, 0.0f);
            *(float4*)(out + base) = ov;
        }
    }
}

// ---------------------------------------------------------------------------
extern "C" void kernel_launch(void* const* d_in, const int* in_sizes, int n_in,
                              void* d_out, int out_size, void* d_ws, size_t ws_size,
                              hipStream_t stream) {
    const float* x     = (const float*)d_in[0];
    const float* w_off = (const float*)d_in[1];
    const float* b_off = (const float*)d_in[2];
    const float* w_def = (const float*)d_in[3];
    const float* gamma = (const float*)d_in[4];
    const float* beta  = (const float*)d_in[5];
    const float* rmean = (const float*)d_in[6];
    const float* rvar  = (const float*)d_in[7];
    float* out = (float*)d_out;

    (void)d_ws; (void)ws_size;   // main path needs no workspace

    fused_deform_kernel<<<NBLK, 256, 0, stream>>>(x, w_off, b_off, w_def,
                                                  gamma, beta, rmean, rvar, out);
}

// Round 18
// 99.187 us; speedup vs baseline: 1.2391x; 1.2391x over previous
//
#include <hip/hip_runtime.h>
#include <math.h>

#define G  17
#define Cg 32
#define B  4
#define C  544
#define H  96
#define W  96
#define HW (H*W)
#define TILES 36         // 6x6 tiles of 16x16 px (transpose: 36 strips of 256)
#define NBLK (B*G*TILES) // 2448 (divisible by 8)
#define BN_EPS 1e-5f

typedef float    f32x4  __attribute__((ext_vector_type(4)));
typedef short    short8 __attribute__((ext_vector_type(8)));
typedef _Float16 h2     __attribute__((ext_vector_type(2)));
typedef _Float16 h8     __attribute__((ext_vector_type(8)));

// ---- fused-kernel LDS: zero-padded WIN=22 window + AffS only.
// B-matrices (w_def, w_off) live in a prepped GLOBAL fp16 table (L2-resident,
// ~466KB total) -> LDS 61.2KB -> 41.8KB -> 3 blocks/CU (+50% waves).
#define WIN       22
#define HALO      3
#define WPOS      (WIN*WIN)       // 484
#define W_STRIDE  80              // 16B-aligned; (pos*20)%32 -> 8 bank starts
#define W_BYTES   (WPOS*W_STRIDE) // 38720
#define AFFS_BYTES 3072           // 256 px x 6 fp16, stride 12B
#define SMEM_BYTES (W_BYTES + AFFS_BYTES) // 41792 -> 3 blocks/CU

#define WDEFT_ELEMS (C*288)       // 544 rows x 288 K, fp16
#define WOT_ELEMS   (G*16*288)    // 17 groups x 16 rows (o>=6 zero) x 288 K
#define PREP_ELEMS  (WDEFT_ELEMS + WOT_ELEMS)

// XCD-chunked swizzle (round-4 verified: FETCH 925->87 MB).
__device__ __forceinline__ int swizzle_blk(int blk) {
    return (blk & 7) * (NBLK / 8) + (blk >> 3);
}

// ---------------------------------------------------------------------------
// Prep: fp16 B-tables.
//   wdefT[c][K=t*32+i] = w_def[c][i][t]          (544x288)
//   woT[g][o][K=t*32+i] = o<6 ? w_off[g*6+o][i][t] : 0   (17x16x288)
// ---------------------------------------------------------------------------
__global__ __launch_bounds__(256) void prep_tables_kernel(
    const float* __restrict__ w_def, const float* __restrict__ w_off,
    _Float16* __restrict__ wdefT, _Float16* __restrict__ woT)
{
    const int idx = blockIdx.x*256 + threadIdx.x;
    if (idx < WDEFT_ELEMS) {
        const int K = idx % 288, c = idx / 288;
        const int t = K >> 5, i = K & 31;
        wdefT[idx] = (_Float16)w_def[(size_t)c*288 + i*9 + t];
    } else if (idx < PREP_ELEMS) {
        const int j = idx - WDEFT_ELEMS;
        const int K = j % 288, o = (j / 288) % 16, g = j / (288*16);
        const int t = K >> 5, i = K & 31;
        const float v = (o < 6) ? w_off[(size_t)(g*6 + o)*288 + i*9 + t] : 0.0f;
        woT[j] = (_Float16)v;
    }
}

// ---------------------------------------------------------------------------
// Kernel T: NCHW f32 -> per-group channels-last FP16 xT[(b*G+g)*HW + p][Cg]
// (round-9/13/16 verified ~20-25us, pure BW)
// ---------------------------------------------------------------------------
__global__ __launch_bounds__(256) void transpose_kernel(
    const float* __restrict__ x, _Float16* __restrict__ xT)
{
    __shared__ float t[256*33];            // +1 pad: conflict-free both phases
    const int blk  = swizzle_blk(blockIdx.x);
    const int tile = blk % TILES;
    const int g    = (blk / TILES) % G;
    const int b    = blk / (TILES*G);

    const float* xg = x + ((size_t)b*C + g*Cg)*HW + tile*256;
    #pragma unroll
    for (int i = 0; i < Cg; ++i)
        t[threadIdx.x*33 + i] = xg[(size_t)i*HW + threadIdx.x];
    __syncthreads();

    h8* dst = (h8*)(xT + ((size_t)(b*G + g)*HW + (size_t)tile*256)*Cg);
    #pragma unroll
    for (int r = 0; r < 4; ++r) {
        const int idx = r*256 + threadIdx.x;    // pixel idx>>2, 8ch (idx&3)*8
        const float* s = &t[(idx >> 2)*33 + (idx & 3)*8];
        h8 o;
        #pragma unroll
        for (int j = 0; j < 8; ++j) o[j] = (_Float16)s[j];
        dst[idx] = o;
    }
}

// ---------------------------------------------------------------------------
// FUSED kernel (R16 structure, B-matrices from global L2-resident tables):
//  1) stage zero-padded 22x22x32 fp16 window from xT (vector loads)
//  2) offset conv via MFMA (B-frag = 16B global load from woT)
//  3) aff redistribute through 3KB AffS
//  4) R15 streamlined deformable sampling + MFMA (B-frag from wdefT)
//     + BN + residual ReLU.
// ---------------------------------------------------------------------------
__global__ __launch_bounds__(256) void fused_deform_kernel(
    const float* __restrict__ x, const _Float16* __restrict__ xT,
    const _Float16* __restrict__ wdefT, const _Float16* __restrict__ woT,
    const float* __restrict__ b_off, const float* __restrict__ gamma,
    const float* __restrict__ beta, const float* __restrict__ rmean,
    const float* __restrict__ rvar, float* __restrict__ out)
{
    __shared__ __align__(16) char smem[SMEM_BYTES];
    char* Wsm  = smem;             // window (zero-padded)
    char* AffS = smem + W_BYTES;   // aff redistribution

    const int blk  = swizzle_blk(blockIdx.x);
    const int tile = blk % TILES;
    const int g    = (blk / TILES) % G;
    const int b    = blk / (TILES*G);
    const int ty   = tile / 6, tx = tile % 6;
    const int h0   = ty*16,    w0 = tx*16;
    const int tid  = threadIdx.x;
    const int lane = tid & 63;
    const int wv   = tid >> 6;
    const int r15  = lane & 15;
    const int koff = lane >> 4;
    const int kb   = koff*16;   // byte offset of this lane's 8-ch slice

    const _Float16* xgT_base = xT + (size_t)(b*G + g)*HW*Cg;

    // ---- 1) stage window to LDS: 484 pos x 64B, ZERO-padded ----
    for (int i = tid; i < WPOS*4; i += 256) {
        const int pos = i >> 2, ch = (i & 3)*8;
        const int wy = pos / WIN, wx = pos % WIN;
        const int y  = h0 + wy - HALO, xx = w0 + wx - HALO;
        short8 v = (short8){0,0,0,0,0,0,0,0};
        if (((unsigned)y < H) && ((unsigned)xx < W))
            v = *(const short8*)(xgT_base + ((size_t)y*W + xx)*Cg + ch);
        *(short8*)(Wsm + pos*W_STRIDE + ch*2) = v;
    }
    __syncthreads();

    // ---- 2) offset conv via MFMA (B from woT global, L2-resident) ----
    const _Float16* woT_g = woT + (size_t)g*16*288 + r15*288 + koff*8;
    f32x4 acc_off[4];
    #pragma unroll
    for (int m = 0; m < 4; ++m) acc_off[m] = (f32x4){0.f, 0.f, 0.f, 0.f};

    #pragma unroll
    for (int t = 0; t < 9; ++t) {
        const int dy = t/3 - 1, dx = t%3 - 1;
        const h8 bo = *(const h8*)(woT_g + t*32);
        #pragma unroll
        for (int m = 0; m < 4; ++m) {
            const int wr = wv*4 + m + dy + HALO;
            const int wc = r15 + dx + HALO;
            const h8 a = *(const h8*)(Wsm + (wr*WIN + wc)*W_STRIDE + kb);
            acc_off[m] = __builtin_amdgcn_mfma_f32_16x16x32_f16(a, bo, acc_off[m], 0, 0, 0);
        }
    }
    __syncthreads();

    // ---- 3) redistribute aff: D[col=r15 -> ch][row=koff*4+r -> px col] ----
    if (r15 < 6) {
        #pragma unroll
        for (int m = 0; m < 4; ++m)
            #pragma unroll
            for (int r = 0; r < 4; ++r) {
                const int lp = (wv*4 + m)*16 + koff*4 + r;
                *(_Float16*)(AffS + lp*12 + r15*2) = (_Float16)acc_off[m][r];
            }
    }
    __syncthreads();

    // ---- readback + bias, pre-folded into window space ----
    const float bo0 = b_off[g*6+0], bo1 = b_off[g*6+1], bo2 = b_off[g*6+2];
    const float bo3 = b_off[g*6+3], bo4 = b_off[g*6+4], bo5 = b_off[g*6+5];
    float a0p[4], a1v[4], a2w[4], a3v[4], a4p[4], a5w[4];
    #pragma unroll
    for (int m = 0; m < 4; ++m) {
        const int row = wv*4 + m;
        const int lp = row*16 + r15;
        const h2 p01 = *(const h2*)(AffS + lp*12);
        const h2 p23 = *(const h2*)(AffS + lp*12 + 4);
        const h2 p45 = *(const h2*)(AffS + lp*12 + 8);
        a0p[m] = (float)p01[0] + bo0 + 1.0f;
        a1v[m] = (float)p01[1] + bo1;
        a2w[m] = (float)p23[0] + bo2 + (float)(row + HALO);
        a3v[m] = (float)p23[1] + bo3;
        a4p[m] = (float)p45[0] + bo4 + 1.0f;
        a5w[m] = (float)p45[1] + bo5 + (float)(r15 + HALO);
    }

    // ---- 4) deformable sampling + MFMA (B from wdefT global) ----
    const _Float16* wd_g0 = wdefT + ((size_t)(g*Cg) + r15)*288 + koff*8;       // n=0
    const _Float16* wd_g1 = wd_g0 + (size_t)16*288;                            // n=1

    f32x4 acc[4][2];
    #pragma unroll
    for (int m = 0; m < 4; ++m)
        #pragma unroll
        for (int n = 0; n < 2; ++n)
            acc[m][n] = (f32x4){0.f, 0.f, 0.f, 0.f};

    #pragma unroll 1
    for (int t = 0; t < 9; ++t) {
        const float kyf = (float)(t/3 - 1);
        const float kxf = (float)(t%3 - 1);

        h8 af[4];
        #pragma unroll
        for (int m = 0; m < 4; ++m) {
            const float pyw = fmaf(a0p[m], kyf, fmaf(a1v[m], kxf, a2w[m]));
            const float pxw = fmaf(a3v[m], kyf, fmaf(a4p[m], kxf, a5w[m]));
            const float y0f = floorf(pyw), x0f = floorf(pxw);
            const float fy = pyw - y0f,   fx = pxw - x0f;
            int iy = (int)y0f, ix = (int)x0f;
            iy = min(max(iy, 0), WIN-2);          // never binds (safety)
            ix = min(max(ix, 0), WIN-2);
            const float gy = 1.0f - fy, gx = 1.0f - fx;
            const float w00 = gy*gx, w01 = gy*fx, w10 = fy*gx, w11 = fy*fx;
            const _Float16 h00 = (_Float16)w00, h01 = (_Float16)w01;
            const _Float16 h10 = (_Float16)w10, h11 = (_Float16)w11;
            const h2 W00 = (h2){h00, h00}, W01 = (h2){h01, h01};
            const h2 W10 = (h2){h10, h10}, W11 = (h2){h11, h11};

            const char* base = Wsm + (iy*WIN + ix)*W_STRIDE + kb;
            union { short8 s; h2 h[4]; h8 v; } u00, u01, u10, u11, r;
            u00.s = *(const short8*)(base);
            u01.s = *(const short8*)(base + W_STRIDE);
            u10.s = *(const short8*)(base + WIN*W_STRIDE);
            u11.s = *(const short8*)(base + WIN*W_STRIDE + W_STRIDE);

            #pragma unroll
            for (int j = 0; j < 4; ++j)
                r.h[j] = W00*u00.h[j] + W01*u01.h[j] + W10*u10.h[j] + W11*u11.h[j];
            af[m] = r.v;
        }

        const h8 bf0 = *(const h8*)(wd_g0 + t*32);
        const h8 bf1 = *(const h8*)(wd_g1 + t*32);
        #pragma unroll
        for (int m = 0; m < 4; ++m) {
            acc[m][0] = __builtin_amdgcn_mfma_f32_16x16x32_f16(af[m], bf0, acc[m][0], 0, 0, 0);
            acc[m][1] = __builtin_amdgcn_mfma_f32_16x16x32_f16(af[m], bf1, acc[m][1], 0, 0, 0);
        }
    }

    // ---- epilogue: BN params hoisted (2 rsqrt), residual + ReLU ----
    float scl[2], shf[2];
    #pragma unroll
    for (int n = 0; n < 2; ++n) {
        const int c = g*Cg + n*16 + r15;
        const float inv = rsqrtf(rvar[c] + BN_EPS);
        scl[n] = inv * gamma[c];
        shf[n] = beta[c] - rmean[c]*scl[n];
    }
    #pragma unroll
    for (int m = 0; m < 4; ++m) {
        const int row = wv*4 + m;
        const int pxg = (h0 + row)*W + w0 + koff*4;     // D row=(lane>>4)*4+reg
        #pragma unroll
        for (int n = 0; n < 2; ++n) {
            const int c = g*Cg + n*16 + r15;
            const size_t base = ((size_t)b*C + c)*HW + pxg;
            const float4 res = *(const float4*)(x + base);
            float4 ov;
            ov.x = fmaxf(fmaf(acc[m][n][0], scl[n], shf[n]) + res.x, 0.0f);
            ov.y = fmaxf(fmaf(acc[m][n][1], scl[n], shf[n]) + res.y, 0.0f);
            ov.z = fmaxf(fmaf(acc[m][n][2], scl[n], shf[n]) + res.z, 0.0f);
            ov.w = fmaxf(fmaf(acc[m][n][3], scl[n], shf[n]) + res.w, 0.0f);
            *(float4*)(out + base) = ov;
        }
    }
}

// ---------------------------------------------------------------------------
// Fallback pair (NCHW f32 path) if ws is too small.
// ---------------------------------------------------------------------------
__global__ __launch_bounds__(256) void offset_conv_kernel(
    const float* __restrict__ x, const float* __restrict__ w_off,
    const float* __restrict__ b_off, float* __restrict__ aff)
{
    __shared__ float wl[Cg*9*6];
    const int blk  = swizzle_blk(blockIdx.x);
    const int tile = blk % TILES;
    const int g    = (blk / TILES) % G;
    const int b    = blk / (TILES*G);

    for (int l = threadIdx.x; l < Cg*9*6; l += 256) {
        int c = l % 6; int t = (l/6) % 9; int i = l/54;
        wl[l] = w_off[(size_t)(g*6 + c)*(Cg*9) + i*9 + t];
    }
    __syncthreads();

    const int p = tile*256 + threadIdx.x;
    const int h = p / W, w = p % W;

    float acc[6];
    #pragma unroll
    for (int c = 0; c < 6; ++c) acc[c] = b_off[g*6 + c];

    const float* xg = x + ((size_t)b*C + g*Cg)*HW;
    for (int i = 0; i < Cg; ++i) {
        const float* xc = xg + (size_t)i*HW;
        #pragma unroll
        for (int t = 0; t < 9; ++t) {
            const int dy = t/3 - 1, dx = t%3 - 1;
            const int yy = h + dy, xx = w + dx;
            float v = (yy >= 0 && yy < H && xx >= 0 && xx < W) ? xc[yy*W + xx] : 0.0f;
            #pragma unroll
            for (int c = 0; c < 6; ++c)
                acc[c] = fmaf(v, wl[(i*9 + t)*6 + c], acc[c]);
        }
    }

    float* ap = aff + ((size_t)(b*G + g)*6)*HW + p;
    #pragma unroll
    for (int c = 0; c < 6; ++c) ap[(size_t)c*HW] = acc[c];
}

__global__ __launch_bounds__(256) void deform_conv_kernel(
    const float* __restrict__ x, const float* __restrict__ w_def,
    const float* __restrict__ aff, const float* __restrict__ gamma,
    const float* __restrict__ beta, const float* __restrict__ rmean,
    const float* __restrict__ rvar, float* __restrict__ out)
{
    __shared__ float wl[9*Cg*Cg];
    const int blk  = swizzle_blk(blockIdx.x);
    const int tile = blk % TILES;
    const int g    = (blk / TILES) % G;
    const int b    = blk / (TILES*G);

    for (int l = threadIdx.x; l < 9*Cg*Cg; l += 256) {
        int o = l & 31; int i = (l >> 5) & 31; int k = l >> 10;
        wl[l] = w_def[(size_t)(g*Cg + o)*(Cg*9) + i*9 + k];
    }
    __syncthreads();

    const int p = tile*256 + threadIdx.x;
    const int h = p / W, w = p % W;

    const float* ap = aff + ((size_t)(b*G + g)*6)*HW + p;
    const float a0 = ap[0*(size_t)HW], a1 = ap[1*(size_t)HW], a2 = ap[2*(size_t)HW];
    const float a3 = ap[3*(size_t)HW], a4 = ap[4*(size_t)HW], a5 = ap[5*(size_t)HW];

    float acc[Cg];
    #pragma unroll
    for (int o = 0; o < Cg; ++o) acc[o] = 0.0f;

    const float* xg = x + ((size_t)b*C + g*Cg)*HW;

    #pragma unroll
    for (int k = 0; k < 9; ++k) {
        const float kyf = (float)(k/3 - 1);
        const float kxf = (float)(k%3 - 1);
        const float offy = a0*kyf + a1*kxf + a2;
        const float offx = a3*kyf + a4*kxf + a5;
        const float py = (float)h + kyf + offy;
        const float px = (float)w + kxf + offx;
        const float y0f = floorf(py), x0f = floorf(px);
        const float fy = py - y0f,   fx = px - x0f;
        const int y0 = (int)y0f, x0 = (int)x0f;
        const int y1 = y0 + 1,   x1 = x0 + 1;
        const bool vy0 = (y0 >= 0) && (y0 < H);
        const bool vy1 = (y1 >= 0) && (y1 < H);
        const bool vx0 = (x0 >= 0) && (x0 < W);
        const bool vx1 = (x1 >= 0) && (x1 < W);
        const float w00 = (vy0 && vx0) ? (1.0f - fy)*(1.0f - fx) : 0.0f;
        const float w01 = (vy0 && vx1) ? (1.0f - fy)*fx          : 0.0f;
        const float w10 = (vy1 && vx0) ? fy*(1.0f - fx)          : 0.0f;
        const float w11 = (vy1 && vx1) ? fy*fx                   : 0.0f;
        const int y0c = min(max(y0, 0), H-1), y1c = min(max(y1, 0), H-1);
        const int x0c = min(max(x0, 0), W-1), x1c = min(max(x1, 0), W-1);
        const int p00 = y0c*W + x0c, p01 = y0c*W + x1c;
        const int p10 = y1c*W + x0c, p11 = y1c*W + x1c;

        const float* wk = &wl[k*Cg*Cg];
        for (int i = 0; i < Cg; ++i) {
            const float* xc = xg + (size_t)i*HW;
            const float v = w00*xc[p00] + w01*xc[p01] + w10*xc[p10] + w11*xc[p11];
            #pragma unroll
            for (int o = 0; o < Cg; ++o)
                acc[o] = fmaf(v, wk[i*Cg + o], acc[o]);
        }
    }

    float* op = out + ((size_t)b*C + g*Cg)*HW + p;
    #pragma unroll
    for (int o = 0; o < Cg; ++o) {
        const int c = g*Cg + o;
        const float inv = rsqrtf(rvar[c] + BN_EPS);
        float val = (acc[o] - rmean[c]) * (inv * gamma[c]) + beta[c];
        val += xg[(size_t)o*HW + p];
        op[(size_t)o*HW] = fmaxf(val, 0.0f);
    }
}

// ---------------------------------------------------------------------------
extern "C" void kernel_launch(void* const* d_in, const int* in_sizes, int n_in,
                              void* d_out, int out_size, void* d_ws, size_t ws_size,
                              hipStream_t stream) {
    const float* x     = (const float*)d_in[0];
    const float* w_off = (const float*)d_in[1];
    const float* b_off = (const float*)d_in[2];
    const float* w_def = (const float*)d_in[3];
    const float* gamma = (const float*)d_in[4];
    const float* beta  = (const float*)d_in[5];
    const float* rmean = (const float*)d_in[6];
    const float* rvar  = (const float*)d_in[7];
    float* out = (float*)d_out;

    const size_t TBL_BYTES = 524288;                               // 512KB slot (need ~466KB)
    const size_t XT_BYTES  = (size_t)B*G*HW*Cg*sizeof(_Float16);   // ~40.1 MB
    const size_t AFF_BYTES = (size_t)B*G*6*HW*sizeof(float);       // ~15.0 MB

    if (ws_size >= TBL_BYTES + XT_BYTES) {
        _Float16* wdefT = (_Float16*)d_ws;
        _Float16* woT   = wdefT + WDEFT_ELEMS;
        _Float16* xT    = (_Float16*)((char*)d_ws + TBL_BYTES);

        prep_tables_kernel<<<(PREP_ELEMS + 255)/256, 256, 0, stream>>>(
            w_def, w_off, wdefT, woT);
        transpose_kernel<<<NBLK, 256, 0, stream>>>(x, xT);
        fused_deform_kernel<<<NBLK, 256, 0, stream>>>(x, xT, wdefT, woT, b_off,
                                                      gamma, beta, rmean, rvar, out);
    } else if (ws_size >= AFF_BYTES) {
        float* aff = (float*)d_ws;
        offset_conv_kernel<<<NBLK, 256, 0, stream>>>(x, w_off, b_off, aff);
        deform_conv_kernel<<<NBLK, 256, 0, stream>>>(x, w_def, aff, gamma, beta,
                                                     rmean, rvar, out);
    }
}

// Round 19
// 98.725 us; speedup vs baseline: 1.2449x; 1.0047x over previous
//
#include <hip/hip_runtime.h>
#include <math.h>

#define G  17
#define Cg 32
#define B  4
#define C  544
#define H  96
#define W  96
#define HW (H*W)
#define TILES 36         // 6x6 tiles of 16x16 px (transpose: 36 strips of 256)
#define NBLK (B*G*TILES) // 2448 (divisible by 8)
#define BN_EPS 1e-5f

typedef float    f32x4  __attribute__((ext_vector_type(4)));
typedef short    short8 __attribute__((ext_vector_type(8)));
typedef _Float16 h2     __attribute__((ext_vector_type(2)));
typedef _Float16 h8     __attribute__((ext_vector_type(8)));

// ---- fused-kernel LDS: ONLY the zero-padded WIN=22 window.
// Each 80B row = 64B data + 16B pad; AffS (256 x 12B) lives in the PAD bytes
// (row lp, offset +64) -> LDS block 38720B -> 4 blocks/CU (was 41984 -> 3).
#define WIN       22
#define HALO      3
#define WPOS      (WIN*WIN)       // 484
#define W_STRIDE  80              // 16B-aligned; (pos*20)%32 -> 8 bank starts
#define W_BYTES   (WPOS*W_STRIDE) // 38720
#define SMEM_BYTES W_BYTES        // 38720 -> 4 blocks/CU

#define WDEFT_ELEMS (C*288)       // 544 rows x 288 K, fp16
#define WOT_ELEMS   (G*16*288)    // 17 groups x 16 rows (o>=6 zero) x 288 K
#define PREP_ELEMS  (WDEFT_ELEMS + WOT_ELEMS)

// XCD-chunked swizzle (round-4 verified: FETCH 925->87 MB).
__device__ __forceinline__ int swizzle_blk(int blk) {
    return (blk & 7) * (NBLK / 8) + (blk >> 3);
}

// ---------------------------------------------------------------------------
// Prep: fp16 B-tables.
//   wdefT[c][K=t*32+i] = w_def[c][i][t]          (544x288)
//   woT[g][o][K=t*32+i] = o<6 ? w_off[g*6+o][i][t] : 0   (17x16x288)
// ---------------------------------------------------------------------------
__global__ __launch_bounds__(256) void prep_tables_kernel(
    const float* __restrict__ w_def, const float* __restrict__ w_off,
    _Float16* __restrict__ wdefT, _Float16* __restrict__ woT)
{
    const int idx = blockIdx.x*256 + threadIdx.x;
    if (idx < WDEFT_ELEMS) {
        const int K = idx % 288, c = idx / 288;
        const int t = K >> 5, i = K & 31;
        wdefT[idx] = (_Float16)w_def[(size_t)c*288 + i*9 + t];
    } else if (idx < PREP_ELEMS) {
        const int j = idx - WDEFT_ELEMS;
        const int K = j % 288, o = (j / 288) % 16, g = j / (288*16);
        const int t = K >> 5, i = K & 31;
        const float v = (o < 6) ? w_off[(size_t)(g*6 + o)*288 + i*9 + t] : 0.0f;
        woT[j] = (_Float16)v;
    }
}

// ---------------------------------------------------------------------------
// Kernel T: NCHW f32 -> per-group channels-last FP16 xT[(b*G+g)*HW + p][Cg]
// (round-9/13/16 verified ~20us, pure BW)
// ---------------------------------------------------------------------------
__global__ __launch_bounds__(256) void transpose_kernel(
    const float* __restrict__ x, _Float16* __restrict__ xT)
{
    __shared__ float t[256*33];            // +1 pad: conflict-free both phases
    const int blk  = swizzle_blk(blockIdx.x);
    const int tile = blk % TILES;
    const int g    = (blk / TILES) % G;
    const int b    = blk / (TILES*G);

    const float* xg = x + ((size_t)b*C + g*Cg)*HW + tile*256;
    #pragma unroll
    for (int i = 0; i < Cg; ++i)
        t[threadIdx.x*33 + i] = xg[(size_t)i*HW + threadIdx.x];
    __syncthreads();

    h8* dst = (h8*)(xT + ((size_t)(b*G + g)*HW + (size_t)tile*256)*Cg);
    #pragma unroll
    for (int r = 0; r < 4; ++r) {
        const int idx = r*256 + threadIdx.x;    // pixel idx>>2, 8ch (idx&3)*8
        const float* s = &t[(idx >> 2)*33 + (idx & 3)*8];
        h8 o;
        #pragma unroll
        for (int j = 0; j < 8; ++j) o[j] = (_Float16)s[j];
        dst[idx] = o;
    }
}

// ---------------------------------------------------------------------------
// FUSED kernel (R18 structure, AffS folded into window-row padding):
//  1) stage zero-padded 22x22x32 fp16 window from xT (vector loads)
//  2) offset conv via MFMA (B-frag = 16B global load from woT, L2-resident)
//  3) aff redistribute through the row-pad bytes (Wsm + lp*80 + 64)
//  4) R15 streamlined deformable sampling + MFMA (B-frag from wdefT)
//     + BN + residual ReLU.
// ---------------------------------------------------------------------------
__global__ __launch_bounds__(256) void fused_deform_kernel(
    const float* __restrict__ x, const _Float16* __restrict__ xT,
    const _Float16* __restrict__ wdefT, const _Float16* __restrict__ woT,
    const float* __restrict__ b_off, const float* __restrict__ gamma,
    const float* __restrict__ beta, const float* __restrict__ rmean,
    const float* __restrict__ rvar, float* __restrict__ out)
{
    __shared__ __align__(16) char smem[SMEM_BYTES];
    char* Wsm = smem;   // window rows: [0..63] data, [64..79] pad (AffS)

    const int blk  = swizzle_blk(blockIdx.x);
    const int tile = blk % TILES;
    const int g    = (blk / TILES) % G;
    const int b    = blk / (TILES*G);
    const int ty   = tile / 6, tx = tile % 6;
    const int h0   = ty*16,    w0 = tx*16;
    const int tid  = threadIdx.x;
    const int lane = tid & 63;
    const int wv   = tid >> 6;
    const int r15  = lane & 15;
    const int koff = lane >> 4;
    const int kb   = koff*16;   // byte offset of this lane's 8-ch slice

    const _Float16* xgT_base = xT + (size_t)(b*G + g)*HW*Cg;

    // ---- 1) stage window to LDS: 484 pos x 64B, ZERO-padded ----
    for (int i = tid; i < WPOS*4; i += 256) {
        const int pos = i >> 2, ch = (i & 3)*8;
        const int wy = pos / WIN, wx = pos % WIN;
        const int y  = h0 + wy - HALO, xx = w0 + wx - HALO;
        short8 v = (short8){0,0,0,0,0,0,0,0};
        if (((unsigned)y < H) && ((unsigned)xx < W))
            v = *(const short8*)(xgT_base + ((size_t)y*W + xx)*Cg + ch);
        *(short8*)(Wsm + pos*W_STRIDE + ch*2) = v;
    }
    __syncthreads();

    // ---- 2) offset conv via MFMA (B from woT global, L2-resident) ----
    const _Float16* woT_g = woT + (size_t)g*16*288 + r15*288 + koff*8;
    f32x4 acc_off[4];
    #pragma unroll
    for (int m = 0; m < 4; ++m) acc_off[m] = (f32x4){0.f, 0.f, 0.f, 0.f};

    #pragma unroll
    for (int t = 0; t < 9; ++t) {
        const int dy = t/3 - 1, dx = t%3 - 1;
        const h8 bo = *(const h8*)(woT_g + t*32);
        #pragma unroll
        for (int m = 0; m < 4; ++m) {
            const int wr = wv*4 + m + dy + HALO;
            const int wc = r15 + dx + HALO;
            const h8 a = *(const h8*)(Wsm + (wr*WIN + wc)*W_STRIDE + kb);
            acc_off[m] = __builtin_amdgcn_mfma_f32_16x16x32_f16(a, bo, acc_off[m], 0, 0, 0);
        }
    }
    __syncthreads();   // offset MFMAs done -> safe to write pads

    // ---- 3) redistribute aff via row pads: slot lp at Wsm+lp*80+64 ----
    if (r15 < 6) {
        #pragma unroll
        for (int m = 0; m < 4; ++m)
            #pragma unroll
            for (int r = 0; r < 4; ++r) {
                const int lp = (wv*4 + m)*16 + koff*4 + r;
                *(_Float16*)(Wsm + lp*W_STRIDE + 64 + r15*2) = (_Float16)acc_off[m][r];
            }
    }
    __syncthreads();

    // ---- readback + bias, pre-folded into window space ----
    const float bo0 = b_off[g*6+0], bo1 = b_off[g*6+1], bo2 = b_off[g*6+2];
    const float bo3 = b_off[g*6+3], bo4 = b_off[g*6+4], bo5 = b_off[g*6+5];
    float a0p[4], a1v[4], a2w[4], a3v[4], a4p[4], a5w[4];
    #pragma unroll
    for (int m = 0; m < 4; ++m) {
        const int row = wv*4 + m;
        const int lp = row*16 + r15;
        const char* slot = Wsm + lp*W_STRIDE + 64;
        const h2 p01 = *(const h2*)(slot);
        const h2 p23 = *(const h2*)(slot + 4);
        const h2 p45 = *(const h2*)(slot + 8);
        a0p[m] = (float)p01[0] + bo0 + 1.0f;
        a1v[m] = (float)p01[1] + bo1;
        a2w[m] = (float)p23[0] + bo2 + (float)(row + HALO);
        a3v[m] = (float)p23[1] + bo3;
        a4p[m] = (float)p45[0] + bo4 + 1.0f;
        a5w[m] = (float)p45[1] + bo5 + (float)(r15 + HALO);
    }

    // ---- 4) deformable sampling + MFMA (B from wdefT global) ----
    const _Float16* wd_g0 = wdefT + ((size_t)(g*Cg) + r15)*288 + koff*8;       // n=0
    const _Float16* wd_g1 = wd_g0 + (size_t)16*288;                            // n=1

    f32x4 acc[4][2];
    #pragma unroll
    for (int m = 0; m < 4; ++m)
        #pragma unroll
        for (int n = 0; n < 2; ++n)
            acc[m][n] = (f32x4){0.f, 0.f, 0.f, 0.f};

    #pragma unroll 1
    for (int t = 0; t < 9; ++t) {
        const float kyf = (float)(t/3 - 1);
        const float kxf = (float)(t%3 - 1);

        h8 af[4];
        #pragma unroll
        for (int m = 0; m < 4; ++m) {
            const float pyw = fmaf(a0p[m], kyf, fmaf(a1v[m], kxf, a2w[m]));
            const float pxw = fmaf(a3v[m], kyf, fmaf(a4p[m], kxf, a5w[m]));
            const float y0f = floorf(pyw), x0f = floorf(pxw);
            const float fy = pyw - y0f,   fx = pxw - x0f;
            int iy = (int)y0f, ix = (int)x0f;
            iy = min(max(iy, 0), WIN-2);          // never binds (safety)
            ix = min(max(ix, 0), WIN-2);
            const float gy = 1.0f - fy, gx = 1.0f - fx;
            const float w00 = gy*gx, w01 = gy*fx, w10 = fy*gx, w11 = fy*fx;
            const _Float16 h00 = (_Float16)w00, h01 = (_Float16)w01;
            const _Float16 h10 = (_Float16)w10, h11 = (_Float16)w11;
            const h2 W00 = (h2){h00, h00}, W01 = (h2){h01, h01};
            const h2 W10 = (h2){h10, h10}, W11 = (h2){h11, h11};

            const char* base = Wsm + (iy*WIN + ix)*W_STRIDE + kb;
            union { short8 s; h2 h[4]; h8 v; } u00, u01, u10, u11, r;
            u00.s = *(const short8*)(base);
            u01.s = *(const short8*)(base + W_STRIDE);
            u10.s = *(const short8*)(base + WIN*W_STRIDE);
            u11.s = *(const short8*)(base + WIN*W_STRIDE + W_STRIDE);

            #pragma unroll
            for (int j = 0; j < 4; ++j)
                r.h[j] = W00*u00.h[j] + W01*u01.h[j] + W10*u10.h[j] + W11*u11.h[j];
            af[m] = r.v;
        }

        const h8 bf0 = *(const h8*)(wd_g0 + t*32);
        const h8 bf1 = *(const h8*)(wd_g1 + t*32);
        #pragma unroll
        for (int m = 0; m < 4; ++m) {
            acc[m][0] = __builtin_amdgcn_mfma_f32_16x16x32_f16(af[m], bf0, acc[m][0], 0, 0, 0);
            acc[m][1] = __builtin_amdgcn_mfma_f32_16x16x32_f16(af[m], bf1, acc[m][1], 0, 0, 0);
        }
    }

    // ---- epilogue: BN params hoisted (2 rsqrt), residual + ReLU ----
    float scl[2], shf[2];
    #pragma unroll
    for (int n = 0; n < 2; ++n) {
        const int c = g*Cg + n*16 + r15;
        const float inv = rsqrtf(rvar[c] + BN_EPS);
        scl[n] = inv * gamma[c];
        shf[n] = beta[c] - rmean[c]*scl[n];
    }
    #pragma unroll
    for (int m = 0; m < 4; ++m) {
        const int row = wv*4 + m;
        const int pxg = (h0 + row)*W + w0 + koff*4;     // D row=(lane>>4)*4+reg
        #pragma unroll
        for (int n = 0; n < 2; ++n) {
            const int c = g*Cg + n*16 + r15;
            const size_t base = ((size_t)b*C + c)*HW + pxg;
            const float4 res = *(const float4*)(x + base);
            float4 ov;
            ov.x = fmaxf(fmaf(acc[m][n][0], scl[n], shf[n]) + res.x, 0.0f);
            ov.y = fmaxf(fmaf(acc[m][n][1], scl[n], shf[n]) + res.y, 0.0f);
            ov.z = fmaxf(fmaf(acc[m][n][2], scl[n], shf[n]) + res.z, 0.0f);
            ov.w = fmaxf(fmaf(acc[m][n][3], scl[n], shf[n]) + res.w, 0.0f);
            *(float4*)(out + base) = ov;
        }
    }
}

// ---------------------------------------------------------------------------
// Fallback pair (NCHW f32 path) if ws is too small.
// ---------------------------------------------------------------------------
__global__ __launch_bounds__(256) void offset_conv_kernel(
    const float* __restrict__ x, const float* __restrict__ w_off,
    const float* __restrict__ b_off, float* __restrict__ aff)
{
    __shared__ float wl[Cg*9*6];
    const int blk  = swizzle_blk(blockIdx.x);
    const int tile = blk % TILES;
    const int g    = (blk / TILES) % G;
    const int b    = blk / (TILES*G);

    for (int l = threadIdx.x; l < Cg*9*6; l += 256) {
        int c = l % 6; int t = (l/6) % 9; int i = l/54;
        wl[l] = w_off[(size_t)(g*6 + c)*(Cg*9) + i*9 + t];
    }
    __syncthreads();

    const int p = tile*256 + threadIdx.x;
    const int h = p / W, w = p % W;

    float acc[6];
    #pragma unroll
    for (int c = 0; c < 6; ++c) acc[c] = b_off[g*6 + c];

    const float* xg = x + ((size_t)b*C + g*Cg)*HW;
    for (int i = 0; i < Cg; ++i) {
        const float* xc = xg + (size_t)i*HW;
        #pragma unroll
        for (int t = 0; t < 9; ++t) {
            const int dy = t/3 - 1, dx = t%3 - 1;
            const int yy = h + dy, xx = w + dx;
            float v = (yy >= 0 && yy < H && xx >= 0 && xx < W) ? xc[yy*W + xx] : 0.0f;
            #pragma unroll
            for (int c = 0; c < 6; ++c)
                acc[c] = fmaf(v, wl[(i*9 + t)*6 + c], acc[c]);
        }
    }

    float* ap = aff + ((size_t)(b*G + g)*6)*HW + p;
    #pragma unroll
    for (int c = 0; c < 6; ++c) ap[(size_t)c*HW] = acc[c];
}

__global__ __launch_bounds__(256) void deform_conv_kernel(
    const float* __restrict__ x, const float* __restrict__ w_def,
    const float* __restrict__ aff, const float* __restrict__ gamma,
    const float* __restrict__ beta, const float* __restrict__ rmean,
    const float* __restrict__ rvar, float* __restrict__ out)
{
    __shared__ float wl[9*Cg*Cg];
    const int blk  = swizzle_blk(blockIdx.x);
    const int tile = blk % TILES;
    const int g    = (blk / TILES) % G;
    const int b    = blk / (TILES*G);

    for (int l = threadIdx.x; l < 9*Cg*Cg; l += 256) {
        int o = l & 31; int i = (l >> 5) & 31; int k = l >> 10;
        wl[l] = w_def[(size_t)(g*Cg + o)*(Cg*9) + i*9 + k];
    }
    __syncthreads();

    const int p = tile*256 + threadIdx.x;
    const int h = p / W, w = p % W;

    const float* ap = aff + ((size_t)(b*G + g)*6)*HW + p;
    const float a0 = ap[0*(size_t)HW], a1 = ap[1*(size_t)HW], a2 = ap[2*(size_t)HW];
    const float a3 = ap[3*(size_t)HW], a4 = ap[4*(size_t)HW], a5 = ap[5*(size_t)HW];

    float acc[Cg];
    #pragma unroll
    for (int o = 0; o < Cg; ++o) acc[o] = 0.0f;

    const float* xg = x + ((size_t)b*C + g*Cg)*HW;

    #pragma unroll
    for (int k = 0; k < 9; ++k) {
        const float kyf = (float)(k/3 - 1);
        const float kxf = (float)(k%3 - 1);
        const float offy = a0*kyf + a1*kxf + a2;
        const float offx = a3*kyf + a4*kxf + a5;
        const float py = (float)h + kyf + offy;
        const float px = (float)w + kxf + offx;
        const float y0f = floorf(py), x0f = floorf(px);
        const float fy = py - y0f,   fx = px - x0f;
        const int y0 = (int)y0f, x0 = (int)x0f;
        const int y1 = y0 + 1,   x1 = x0 + 1;
        const bool vy0 = (y0 >= 0) && (y0 < H);
        const bool vy1 = (y1 >= 0) && (y1 < H);
        const bool vx0 = (x0 >= 0) && (x0 < W);
        const bool vx1 = (x1 >= 0) && (x1 < W);
        const float w00 = (vy0 && vx0) ? (1.0f - fy)*(1.0f - fx) : 0.0f;
        const float w01 = (vy0 && vx1) ? (1.0f - fy)*fx          : 0.0f;
        const float w10 = (vy1 && vx0) ? fy*(1.0f - fx)          : 0.0f;
        const float w11 = (vy1 && vx1) ? fy*fx                   : 0.0f;
        const int y0c = min(max(y0, 0), H-1), y1c = min(max(y1, 0), H-1);
        const int x0c = min(max(x0, 0), W-1), x1c = min(max(x1, 0), W-1);
        const int p00 = y0c*W + x0c, p01 = y0c*W + x1c;
        const int p10 = y1c*W + x0c, p11 = y1c*W + x1c;

        const float* wk = &wl[k*Cg*Cg];
        for (int i = 0; i < Cg; ++i) {
            const float* xc = xg + (size_t)i*HW;
            const float v = w00*xc[p00] + w01*xc[p01] + w10*xc[p10] + w11*xc[p11];
            #pragma unroll
            for (int o = 0; o < Cg; ++o)
                acc[o] = fmaf(v, wk[i*Cg + o], acc[o]);
        }
    }

    float* op = out + ((size_t)b*C + g*Cg)*HW + p;
    #pragma unroll
    for (int o = 0; o < Cg; ++o) {
        const int c = g*Cg + o;
        const float inv = rsqrtf(rvar[c] + BN_EPS);
        float val = (acc[o] - rmean[c]) * (inv * gamma[c]) + beta[c];
        val += xg[(size_t)o*HW + p];
        op[(size_t)o*HW] = fmaxf(val, 0.0f);
    }
}

// ---------------------------------------------------------------------------
extern "C" void kernel_launch(void* const* d_in, const int* in_sizes, int n_in,
                              void* d_out, int out_size, void* d_ws, size_t ws_size,
                              hipStream_t stream) {
    const float* x     = (const float*)d_in[0];
    const float* w_off = (const float*)d_in[1];
    const float* b_off = (const float*)d_in[2];
    const float* w_def = (const float*)d_in[3];
    const float* gamma = (const float*)d_in[4];
    const float* beta  = (const float*)d_in[5];
    const float* rmean = (const float*)d_in[6];
    const float* rvar  = (const float*)d_in[7];
    float* out = (float*)d_out;

    const size_t TBL_BYTES = 524288;                               // 512KB slot (need ~466KB)
    const size_t XT_BYTES  = (size_t)B*G*HW*Cg*sizeof(_Float16);   // ~40.1 MB
    const size_t AFF_BYTES = (size_t)B*G*6*HW*sizeof(float);       // ~15.0 MB

    if (ws_size >= TBL_BYTES + XT_BYTES) {
        _Float16* wdefT = (_Float16*)d_ws;
        _Float16* woT   = wdefT + WDEFT_ELEMS;
        _Float16* xT    = (_Float16*)((char*)d_ws + TBL_BYTES);

        prep_tables_kernel<<<(PREP_ELEMS + 255)/256, 256, 0, stream>>>(
            w_def, w_off, wdefT, woT);
        transpose_kernel<<<NBLK, 256, 0, stream>>>(x, xT);
        fused_deform_kernel<<<NBLK, 256, 0, stream>>>(x, xT, wdefT, woT, b_off,
                                                      gamma, beta, rmean, rvar, out);
    } else if (ws_size >= AFF_BYTES) {
        float* aff = (float*)d_ws;
        offset_conv_kernel<<<NBLK, 256, 0, stream>>>(x, w_off, b_off, aff);
        deform_conv_kernel<<<NBLK, 256, 0, stream>>>(x, w_def, aff, gamma, beta,
                                                     rmean, rvar, out);
    }
}